// Round 11
// baseline (188.709 us; speedup 1.0000x reference)
//
#include <hip/hip_runtime.h>

typedef __bf16 bf16x8 __attribute__((ext_vector_type(8)));
typedef float f32x4 __attribute__((ext_vector_type(4)));

__device__ __forceinline__ unsigned short f2bf(float f) {
  union { float f; unsigned u; } v; v.f = f;
  unsigned u = v.u;
  return (unsigned short)((u + 0x7fffu + ((u >> 16) & 1u)) >> 16);  // RNE
}
__device__ __forceinline__ unsigned short f2bf_fast(float f) {
  union { float f; unsigned u; } v; v.f = f;
  return (unsigned short)((v.u + 0x8000u) >> 16);  // round-half-up, for P only
}
__device__ __forceinline__ void gload_lds16(const void* g, void* l) {
  __builtin_amdgcn_global_load_lds(
      (const __attribute__((address_space(1))) unsigned int*)g,
      (__attribute__((address_space(3))) unsigned int*)l, 16, 0, 0);
}
__device__ __forceinline__ void cvt4(const float* __restrict__ s,
                                     unsigned short* __restrict__ d, int u) {
  f32x4 v = ((const f32x4*)s)[u];
  union { unsigned short s[4]; unsigned long long u; } o;
  o.s[0] = f2bf(v[0]); o.s[1] = f2bf(v[1]); o.s[2] = f2bf(v[2]); o.s[3] = f2bf(v[3]);
  ((unsigned long long*)d)[u] = o.u;
}

// LDS tile swizzle: row r, 16B-chunk c stored at chunk position c ^ (r&7).
// Staging lane fetches global chunk (ln&7)^(ln>>3); reads XOR chunk with lq&7.

// ---------------- prep: f32->bf16 conversions + ebj, one launch -------------
__global__ void prep(const float* __restrict__ x, const float* __restrict__ W1,
                     const float* __restrict__ Wv, const float* __restrict__ Wp,
                     const float* __restrict__ w2, const float* __restrict__ b2,
                     unsigned short* __restrict__ xb, unsigned short* __restrict__ W1b,
                     unsigned short* __restrict__ Wvb, unsigned short* __restrict__ Wpb,
                     unsigned short* __restrict__ w2t, unsigned short* __restrict__ ebj) {
  int u = blockIdx.x * 256 + threadIdx.x;
  if (u < 1048576) { cvt4(x, xb, u); return; }
  u -= 1048576;
  if (u < 262144) { cvt4(W1, W1b, u); return; }
  u -= 262144;
  if (u < 262144) { cvt4(Wv, Wvb, u); return; }
  u -= 262144;
  if (u < 262144) { cvt4(Wp, Wpb, u); return; }
  u -= 262144;
  if (u < 32768) {
    // w2 (64,2048) f32 -> w2t (2048,64) bf16
    int j = u >> 4, d4 = (u & 15) * 4;
    union { unsigned short s[4]; unsigned long long x; } o;
#pragma unroll
    for (int i = 0; i < 4; ++i) o.s[i] = f2bf(w2[(d4 + i) * 2048 + j]);
    ((unsigned long long*)w2t)[u] = o.x;
    return;
  }
  u -= 32768;
  // ebj = bf16(exp(b2)), 2048 elems in 512 x4-units
  union { unsigned short s[4]; unsigned long long x; } o;
#pragma unroll
  for (int i = 0; i < 4; ++i) o.s[i] = f2bf(__expf(b2[u * 4 + i]));
  ((unsigned long long*)ebj)[u] = o.x;
}

// ---------------- merged r & vt GEMM: 128M x 64N tiles, 1024 blocks ---------
// id<512:  rb = relu(xb @ W1b^T + b1)            M=4096 N=1024  (32x16)
// id>=512: vt = (Wvb @ xb^T + bv[row])*exp(b2[col&2047])  M=1024 N=4096 (8x64)
// 24KB LDS, 4 blocks/CU co-resident (16 waves/CU) to hide staging latency.
__global__ __launch_bounds__(256) void gemm_rv(
    const unsigned short* __restrict__ xb, const unsigned short* __restrict__ W1b,
    const unsigned short* __restrict__ Wvb, const float* __restrict__ b1,
    const float* __restrict__ bv, const float* __restrict__ b2,
    unsigned short* __restrict__ rb, unsigned short* __restrict__ vtb) {
  __shared__ unsigned short As[128 * 64];
  __shared__ unsigned short Bs[64 * 64];
  int id = blockIdx.x;
  const unsigned short *A, *Bt;
  const float* bias;
  unsigned short* C;
  int N, tileM, tileN, epi;
  if (id < 512) {
    A = xb; Bt = W1b; bias = b1; C = rb; N = 1024; epi = 0;
    tileN = (id & 15) * 64; tileM = (id >> 4) * 128;
  } else {
    id -= 512;
    A = Wvb; Bt = xb; bias = bv; C = vtb; N = 4096; epi = 1;
    tileN = (id & 63) * 64; tileM = (id >> 6) * 128;
  }
  const int tid = threadIdx.x;
  const int wv = tid >> 6, ln = tid & 63;
  const int quad = ln >> 4, lq = ln & 15;
  const int rowL = ln >> 3;
  const int kc = (((ln & 7) ^ rowL) & 7) * 8;
  const int sx = lq & 7;
  const int ko0 = (quad ^ sx) * 8, ko1 = ((4 + quad) ^ sx) * 8;

  f32x4 acc[2][4];
  const f32x4 zf = {0.f, 0.f, 0.f, 0.f};
#pragma unroll
  for (int i = 0; i < 2; ++i)
#pragma unroll
    for (int j = 0; j < 4; ++j) acc[i][j] = zf;

  for (int k0 = 0; k0 < 1024; k0 += 64) {
    __syncthreads();
#pragma unroll
    for (int l = 0; l < 4; ++l) {
      int row = l * 32 + wv * 8 + rowL;
      gload_lds16(A + (tileM + row) * 1024 + k0 + kc, &As[l * 2048 + wv * 512]);
    }
#pragma unroll
    for (int l = 0; l < 2; ++l) {
      int row = l * 32 + wv * 8 + rowL;
      gload_lds16(Bt + (tileN + row) * 1024 + k0 + kc, &Bs[l * 2048 + wv * 512]);
    }
    __syncthreads();
#pragma unroll
    for (int kk = 0; kk < 2; ++kk) {
      const int ko = kk ? ko1 : ko0;
      bf16x8 af[2], bfr[4];
#pragma unroll
      for (int mi = 0; mi < 2; ++mi)
        af[mi] = *(const bf16x8*)&As[(wv * 32 + mi * 16 + lq) * 64 + ko];
#pragma unroll
      for (int ni = 0; ni < 4; ++ni)
        bfr[ni] = *(const bf16x8*)&Bs[(ni * 16 + lq) * 64 + ko];
#pragma unroll
      for (int mi = 0; mi < 2; ++mi)
#pragma unroll
        for (int ni = 0; ni < 4; ++ni)
          acc[mi][ni] = __builtin_amdgcn_mfma_f32_16x16x32_bf16(af[mi], bfr[ni], acc[mi][ni], 0, 0, 0);
    }
  }
#pragma unroll
  for (int ni = 0; ni < 4; ++ni) {
    int col = tileN + ni * 16 + lq;
    float eb = (epi == 1) ? __expf(b2[col & 2047]) : 0.0f;
#pragma unroll
    for (int mi = 0; mi < 2; ++mi) {
#pragma unroll
      for (int rg = 0; rg < 4; ++rg) {
        int row = tileM + wv * 32 + mi * 16 + quad * 4 + rg;
        float v = acc[mi][ni][rg];
        if (epi == 0) {
          v += bias[col];
          v = v > 0.f ? v : 0.f;
        } else {
          v = (v + bias[row]) * eb;
        }
        C[row * N + col] = f2bf(v);
      }
    }
  }
}

// ---------------- final GEMM: d_out = yb @ Wp^T + bp (f32 out) --------------
// 64M x 64N tiles -> grid (16,64) = 1024 blocks = 4/CU (16KB LDS).
__global__ __launch_bounds__(256) void gemm_p(
    const unsigned short* __restrict__ A, const unsigned short* __restrict__ Bt,
    const float* __restrict__ bias, float* __restrict__ C) {
  __shared__ unsigned short As[64 * 64];
  __shared__ unsigned short Bs[64 * 64];
  const int tid = threadIdx.x;
  const int wv = tid >> 6, ln = tid & 63;
  const int quad = ln >> 4, lq = ln & 15;
  const int tileM = blockIdx.y * 64, tileN = blockIdx.x * 64;
  const int rowL = ln >> 3;
  const int kc = (((ln & 7) ^ rowL) & 7) * 8;
  const int sx = lq & 7;
  const int ko0 = (quad ^ sx) * 8, ko1 = ((4 + quad) ^ sx) * 8;

  f32x4 acc[4];
  const f32x4 zf = {0.f, 0.f, 0.f, 0.f};
#pragma unroll
  for (int j = 0; j < 4; ++j) acc[j] = zf;

  for (int k0 = 0; k0 < 1024; k0 += 64) {
    __syncthreads();
#pragma unroll
    for (int l = 0; l < 2; ++l) {
      int row = l * 32 + wv * 8 + rowL;
      gload_lds16(A + (tileM + row) * 1024 + k0 + kc, &As[l * 2048 + wv * 512]);
      gload_lds16(Bt + (tileN + row) * 1024 + k0 + kc, &Bs[l * 2048 + wv * 512]);
    }
    __syncthreads();
#pragma unroll
    for (int kk = 0; kk < 2; ++kk) {
      const int ko = kk ? ko1 : ko0;
      bf16x8 af = *(const bf16x8*)&As[(wv * 16 + lq) * 64 + ko];
#pragma unroll
      for (int ni = 0; ni < 4; ++ni) {
        bf16x8 bfr = *(const bf16x8*)&Bs[(ni * 16 + lq) * 64 + ko];
        acc[ni] = __builtin_amdgcn_mfma_f32_16x16x32_bf16(af, bfr, acc[ni], 0, 0, 0);
      }
    }
  }
#pragma unroll
  for (int ni = 0; ni < 4; ++ni) {
    int col = tileN + ni * 16 + lq;
#pragma unroll
    for (int rg = 0; rg < 4; ++rg) {
      int row = tileM + wv * 16 + quad * 4 + rg;
      C[row * 1024 + col] = acc[ni][rg] + bias[col];
    }
  }
}

// ---------------- fused synthesizer attention (uniform sequential pairs) ----
// Block = tiles (p, 31-p) processed sequentially: phase A = tile p (j 0..p),
// phase B = tile 31-p (j 0..31-p) -> exactly 33 j-iterations per block.
// Grid (16,32)=512 blocks, 2/CU, all identical duration -> no tail.
// Body/staging/LDS identical to the proven round-6 kernel.
__global__ __launch_bounds__(256, 2) void attn(
    const unsigned short* __restrict__ r, const unsigned short* __restrict__ w2t,
    const unsigned short* __restrict__ vt, const unsigned short* __restrict__ ebj,
    unsigned short* __restrict__ y) {
  __shared__ unsigned short W2s[2][64 * 64];
  __shared__ unsigned short Vs[2][64 * 64];
  __shared__ unsigned short Ps[4][16 * 64];

  const int tid = threadIdx.x;
  const int wv = tid >> 6, ln = tid & 63;
  const int quad = ln >> 4, lq = ln & 15;
  const int p = blockIdx.x;                       // pair (p, 31-p)
  const int bh = blockIdx.y, b = bh >> 4, h = bh & 15;
  const int ta = p, tb = 31 - p;
  const int t0a = ta * 64, t0b = tb * 64;
  const int rowL = ln >> 3;
  const int kc = (((ln & 7) ^ rowL) & 7) * 8;
  const int sx = lq & 7;
  const int ko0 = (quad ^ sx) * 8, ko1 = ((4 + quad) ^ sx) * 8;

  // R A-fragments for both tiles (L2/L3-hot)
  bf16x8 ra[2][2];
  {
    const unsigned short* base = r + (b * 2048 + wv * 16 + lq) * 1024 + h * 64 + quad * 8;
    ra[0][0] = *(const bf16x8*)(base + t0a * 1024);
    ra[0][1] = *(const bf16x8*)(base + t0a * 1024 + 32);
    ra[1][0] = *(const bf16x8*)(base + t0b * 1024);
    ra[1][1] = *(const bf16x8*)(base + t0b * 1024 + 32);
  }

  f32x4 accY[4];
  f32x4 accL;
  const f32x4 zf = {0.f, 0.f, 0.f, 0.f};
#pragma unroll
  for (int nd = 0; nd < 4; ++nd) accY[nd] = zf;
  accL = zf;

  auto stage = [&](int jt, int bi) {
    int j0 = jt * 64;
#pragma unroll
    for (int l = 0; l < 2; ++l) {
      int row = l * 32 + wv * 8 + rowL;
      gload_lds16(w2t + (j0 + row) * 64 + kc, &W2s[bi][l * 2048 + wv * 512]);
      gload_lds16(vt + (h * 64 + row) * 4096 + b * 2048 + j0 + kc,
                  &Vs[bi][l * 2048 + wv * 512]);
    }
  };

  stage(0, 0);
  for (int it = 0; it <= 32; ++it) {
    const int cb = it & 1;
    __syncthreads();                 // staging(it) landed; other buf free
    if (it < 32) {
      int nit = it + 1;
      int njt = (nit <= p) ? nit : (nit - p - 1);
      stage(njt, cb ^ 1);
    }
    const int s = (it <= p) ? 0 : 1;
    const int jt = (it <= p) ? it : (it - p - 1);
    const int tts = s ? tb : ta;
    const int t0 = tts * 64;
    const int j0 = jt * 64;

    // ebj B-fragments for the L-MFMA
    bf16x8 eb0 = *(const bf16x8*)&ebj[j0 + quad * 8];
    bf16x8 eb1 = *(const bf16x8*)&ebj[j0 + 32 + quad * 8];
    // W2 B-fragments
    bf16x8 w2f0[4], w2f1[4];
#pragma unroll
    for (int ni = 0; ni < 4; ++ni) {
      w2f0[ni] = *(const bf16x8*)&W2s[cb][(ni * 16 + lq) * 64 + ko0];
      w2f1[ni] = *(const bf16x8*)&W2s[cb][(ni * 16 + lq) * 64 + ko1];
    }

    // S = R(16x64) @ W2^T -> C rows t=quad*4+rg, col j=lq (per ni)
    f32x4 sv[4] = {zf, zf, zf, zf};
#pragma unroll
    for (int ni = 0; ni < 4; ++ni) {
      sv[ni] = __builtin_amdgcn_mfma_f32_16x16x32_bf16(ra[s][0], w2f0[ni], sv[ni], 0, 0, 0);
      sv[ni] = __builtin_amdgcn_mfma_f32_16x16x32_bf16(ra[s][1], w2f1[ni], sv[ni], 0, 0, 0);
    }

    // exp (+ causal mask on diag tile), write P to LDS (A-layout, swizzled)
    const bool diag = (jt == tts);
#pragma unroll
    for (int ni = 0; ni < 4; ++ni) {
      int j = j0 + ni * 16 + lq;
#pragma unroll
      for (int rg = 0; rg < 4; ++rg) {
        float pe = __expf(sv[ni][rg]);
        if (diag) {
          int t = t0 + wv * 16 + quad * 4 + rg;
          pe = (j <= t) ? pe : 0.f;
        }
        Ps[wv][(quad * 4 + rg) * 64 +
               (((ni * 2 + (lq >> 3)) ^ ((quad * 4 + rg) & 7)) * 8) + (lq & 7)] = f2bf_fast(pe);
      }
    }

    // Y += P(16x64) @ V(64x64); L += P @ ebj
#pragma unroll
    for (int kk = 0; kk < 2; ++kk) {
      const int ko = kk ? ko1 : ko0;
      bf16x8 pa = *(const bf16x8*)&Ps[wv][lq * 64 + ko];
#pragma unroll
      for (int nd = 0; nd < 4; ++nd) {
        bf16x8 bb = *(const bf16x8*)&Vs[cb][(nd * 16 + lq) * 64 + ko];
        accY[nd] = __builtin_amdgcn_mfma_f32_16x16x32_bf16(pa, bb, accY[nd], 0, 0, 0);
      }
      accL = __builtin_amdgcn_mfma_f32_16x16x32_bf16(pa, kk ? eb1 : eb0, accL, 0, 0, 0);
    }

    // phase epilogue: write this tile's y, reset accumulators for phase B
    if (it == p || it == 32) {
      float inv[4];
#pragma unroll
      for (int rg = 0; rg < 4; ++rg) inv[rg] = __builtin_amdgcn_rcpf(accL[rg]);
#pragma unroll
      for (int nd = 0; nd < 4; ++nd)
#pragma unroll
        for (int rg = 0; rg < 4; ++rg) {
          int t = t0 + wv * 16 + quad * 4 + rg;
          y[(b * 2048 + t) * 1024 + h * 64 + nd * 16 + lq] = f2bf(accY[nd][rg] * inv[rg]);
        }
#pragma unroll
      for (int nd = 0; nd < 4; ++nd) accY[nd] = zf;
      accL = zf;
    }
  }
}

// ---------------- launch ----------------
extern "C" void kernel_launch(void* const* d_in, const int* in_sizes, int n_in,
                              void* d_out, int out_size, void* d_ws, size_t ws_size,
                              hipStream_t stream) {
  const float* x  = (const float*)d_in[0];
  const float* W1 = (const float*)d_in[1];
  const float* b1 = (const float*)d_in[2];
  const float* w2 = (const float*)d_in[3];
  const float* b2 = (const float*)d_in[4];
  const float* Wv = (const float*)d_in[5];
  const float* bv = (const float*)d_in[6];
  const float* Wp = (const float*)d_in[7];
  const float* bp = (const float*)d_in[8];

  unsigned short* ws  = (unsigned short*)d_ws;
  unsigned short* xb   = ws;                 // 4096x1024 bf16
  unsigned short* W1b  = ws + 4194304;       // 1024x1024
  unsigned short* Wvb  = ws + 5242880;       // 1024x1024
  unsigned short* Wpb  = ws + 6291456;       // 1024x1024
  unsigned short* w2t  = ws + 7340032;       // 2048x64
  unsigned short* rb   = ws + 7471104;       // 4096x1024
  unsigned short* vt   = ws + 11665408;      // 1024x4096
  unsigned short* yb   = ws + 15859712;      // 4096x1024 bf16
  unsigned short* ebjb = ws + 20054016;      // 2048 bf16

  prep<<<7298, 256, 0, stream>>>(x, W1, Wv, Wp, w2, b2, xb, W1b, Wvb, Wpb, w2t, ebjb);
  gemm_rv<<<1024, 256, 0, stream>>>(xb, W1b, Wvb, b1, bv, b2, rb, vt);
  attn<<<dim3(16, 32), 256, 0, stream>>>(rb, w2t, vt, ebjb, yb);
  gemm_p<<<dim3(16, 64), 256, 0, stream>>>(yb, Wpb, bp, (float*)d_out);
}

// Round 12
// 182.433 us; speedup vs baseline: 1.0344x; 1.0344x over previous
//
#include <hip/hip_runtime.h>

typedef __bf16 bf16x8 __attribute__((ext_vector_type(8)));
typedef float f32x4 __attribute__((ext_vector_type(4)));

__device__ __forceinline__ unsigned short f2bf(float f) {
  union { float f; unsigned u; } v; v.f = f;
  unsigned u = v.u;
  return (unsigned short)((u + 0x7fffu + ((u >> 16) & 1u)) >> 16);  // RNE
}
__device__ __forceinline__ unsigned short f2bf_fast(float f) {
  union { float f; unsigned u; } v; v.f = f;
  return (unsigned short)((v.u + 0x8000u) >> 16);  // round-half-up, for P only
}
__device__ __forceinline__ void gload_lds16(const void* g, void* l) {
  __builtin_amdgcn_global_load_lds(
      (const __attribute__((address_space(1))) unsigned int*)g,
      (__attribute__((address_space(3))) unsigned int*)l, 16, 0, 0);
}
__device__ __forceinline__ void cvt4(const float* __restrict__ s,
                                     unsigned short* __restrict__ d, int u) {
  f32x4 v = ((const f32x4*)s)[u];
  union { unsigned short s[4]; unsigned long long u; } o;
  o.s[0] = f2bf(v[0]); o.s[1] = f2bf(v[1]); o.s[2] = f2bf(v[2]); o.s[3] = f2bf(v[3]);
  ((unsigned long long*)d)[u] = o.u;
}

// LDS tile swizzle: row r, 16B-chunk c stored at chunk position c ^ (r&7).
// Staging lane fetches global chunk (ln&7)^(ln>>3); reads XOR chunk with lq&7.

// ---------------- prep: f32->bf16 conversions + ebj, one launch -------------
__global__ void prep(const float* __restrict__ x, const float* __restrict__ W1,
                     const float* __restrict__ Wv, const float* __restrict__ Wp,
                     const float* __restrict__ w2, const float* __restrict__ b2,
                     unsigned short* __restrict__ xb, unsigned short* __restrict__ W1b,
                     unsigned short* __restrict__ Wvb, unsigned short* __restrict__ Wpb,
                     unsigned short* __restrict__ w2t, unsigned short* __restrict__ ebj) {
  int u = blockIdx.x * 256 + threadIdx.x;
  if (u < 1048576) { cvt4(x, xb, u); return; }
  u -= 1048576;
  if (u < 262144) { cvt4(W1, W1b, u); return; }
  u -= 262144;
  if (u < 262144) { cvt4(Wv, Wvb, u); return; }
  u -= 262144;
  if (u < 262144) { cvt4(Wp, Wpb, u); return; }
  u -= 262144;
  if (u < 32768) {
    // w2 (64,2048) f32 -> w2t (2048,64) bf16
    int j = u >> 4, d4 = (u & 15) * 4;
    union { unsigned short s[4]; unsigned long long x; } o;
#pragma unroll
    for (int i = 0; i < 4; ++i) o.s[i] = f2bf(w2[(d4 + i) * 2048 + j]);
    ((unsigned long long*)w2t)[u] = o.x;
    return;
  }
  u -= 32768;
  // ebj = bf16(exp(b2)), 2048 elems in 512 x4-units
  union { unsigned short s[4]; unsigned long long x; } o;
#pragma unroll
  for (int i = 0; i < 4; ++i) o.s[i] = f2bf(__expf(b2[u * 4 + i]));
  ((unsigned long long*)ebj)[u] = o.x;
}

// ---------------- fused r & vt GEMM: shared xb tile ------------------------
// Block (tokT=x, nT=y), grid (32,16). Stages xb[128tok x 64k] ONCE; uses it
// as A for r (rb[tm..tm+128, n0..n0+64] = relu(xb@W1^T+b1)) and as B for vt
// (vt[n0..n0+64, tm..tm+128] = (Wv@xb^T+bv)*exp(b2)). 16 MFMA + 8 gll per
// wave-interval (vs 8+6 unfused). id%8 = tokT%8 -> xb tile L2-co-located.
__global__ __launch_bounds__(256) void gemm_rv(
    const unsigned short* __restrict__ xb, const unsigned short* __restrict__ W1b,
    const unsigned short* __restrict__ Wvb, const float* __restrict__ b1,
    const float* __restrict__ bv, const float* __restrict__ b2,
    unsigned short* __restrict__ rb, unsigned short* __restrict__ vtb) {
  __shared__ unsigned short Xs[128 * 64];
  __shared__ unsigned short W1s[64 * 64];
  __shared__ unsigned short Wvs[64 * 64];
  const int tm = blockIdx.x * 128, n0 = blockIdx.y * 64;
  const int tid = threadIdx.x;
  const int wv = tid >> 6, ln = tid & 63;
  const int quad = ln >> 4, lq = ln & 15;
  const int rowL = ln >> 3;
  const int kc = (((ln & 7) ^ rowL) & 7) * 8;
  const int sx = lq & 7;
  const int ko0 = (quad ^ sx) * 8, ko1 = ((4 + quad) ^ sx) * 8;

  f32x4 accR[2][4];
  f32x4 accV[8];
  const f32x4 zf = {0.f, 0.f, 0.f, 0.f};
#pragma unroll
  for (int i = 0; i < 2; ++i)
#pragma unroll
    for (int j = 0; j < 4; ++j) accR[i][j] = zf;
#pragma unroll
  for (int j = 0; j < 8; ++j) accV[j] = zf;

  for (int k0 = 0; k0 < 1024; k0 += 64) {
    __syncthreads();
#pragma unroll
    for (int l = 0; l < 4; ++l) {
      int row = l * 32 + wv * 8 + rowL;
      gload_lds16(xb + (tm + row) * 1024 + k0 + kc, &Xs[l * 2048 + wv * 512]);
    }
#pragma unroll
    for (int l = 0; l < 2; ++l) {
      int row = l * 32 + wv * 8 + rowL;
      gload_lds16(W1b + (n0 + row) * 1024 + k0 + kc, &W1s[l * 2048 + wv * 512]);
      gload_lds16(Wvb + (n0 + row) * 1024 + k0 + kc, &Wvs[l * 2048 + wv * 512]);
    }
    __syncthreads();
#pragma unroll
    for (int kk = 0; kk < 2; ++kk) {
      const int ko = kk ? ko1 : ko0;
      // r: A = Xs rows (wv*32 + mi*16 + lq), B = W1s rows (ni*16 + lq)
      bf16x8 xa[2], w1f[4];
#pragma unroll
      for (int mi = 0; mi < 2; ++mi)
        xa[mi] = *(const bf16x8*)&Xs[(wv * 32 + mi * 16 + lq) * 64 + ko];
#pragma unroll
      for (int ni = 0; ni < 4; ++ni)
        w1f[ni] = *(const bf16x8*)&W1s[(ni * 16 + lq) * 64 + ko];
#pragma unroll
      for (int mi = 0; mi < 2; ++mi)
#pragma unroll
        for (int ni = 0; ni < 4; ++ni)
          accR[mi][ni] = __builtin_amdgcn_mfma_f32_16x16x32_bf16(xa[mi], w1f[ni], accR[mi][ni], 0, 0, 0);
      // vt: A = Wvs row (wv*16 + lq), B = Xs rows (nj*16 + lq), 8 tok-frags
      bf16x8 wva = *(const bf16x8*)&Wvs[(wv * 16 + lq) * 64 + ko];
#pragma unroll
      for (int nj = 0; nj < 8; ++nj) {
        bf16x8 xbf = *(const bf16x8*)&Xs[(nj * 16 + lq) * 64 + ko];
        accV[nj] = __builtin_amdgcn_mfma_f32_16x16x32_bf16(wva, xbf, accV[nj], 0, 0, 0);
      }
    }
  }
  // epilogue r
#pragma unroll
  for (int ni = 0; ni < 4; ++ni) {
    int col = n0 + ni * 16 + lq;
    float bc = b1[col];
#pragma unroll
    for (int mi = 0; mi < 2; ++mi)
#pragma unroll
      for (int rg = 0; rg < 4; ++rg) {
        int row = tm + wv * 32 + mi * 16 + quad * 4 + rg;
        float v = accR[mi][ni][rg] + bc;
        rb[row * 1024 + col] = f2bf(v > 0.f ? v : 0.f);
      }
  }
  // epilogue vt
#pragma unroll
  for (int nj = 0; nj < 8; ++nj) {
    int tok = tm + nj * 16 + lq;
    float eb = __expf(b2[tok & 2047]);
#pragma unroll
    for (int rg = 0; rg < 4; ++rg) {
      int ch = n0 + wv * 16 + quad * 4 + rg;
      vtb[ch * 4096 + tok] = f2bf((accV[nj][rg] + bv[ch]) * eb);
    }
  }
}

// ---------------- final GEMM: d_out = yb @ Wp^T + bp (f32 out) --------------
// 64M x 64N tiles -> grid (16,64) = 1024 blocks = 4/CU (16KB LDS).
__global__ __launch_bounds__(256) void gemm_p(
    const unsigned short* __restrict__ A, const unsigned short* __restrict__ Bt,
    const float* __restrict__ bias, float* __restrict__ C) {
  __shared__ unsigned short As[64 * 64];
  __shared__ unsigned short Bs[64 * 64];
  const int tid = threadIdx.x;
  const int wv = tid >> 6, ln = tid & 63;
  const int quad = ln >> 4, lq = ln & 15;
  const int tileM = blockIdx.y * 64, tileN = blockIdx.x * 64;
  const int rowL = ln >> 3;
  const int kc = (((ln & 7) ^ rowL) & 7) * 8;
  const int sx = lq & 7;
  const int ko0 = (quad ^ sx) * 8, ko1 = ((4 + quad) ^ sx) * 8;

  f32x4 acc[4];
  const f32x4 zf = {0.f, 0.f, 0.f, 0.f};
#pragma unroll
  for (int j = 0; j < 4; ++j) acc[j] = zf;

  for (int k0 = 0; k0 < 1024; k0 += 64) {
    __syncthreads();
#pragma unroll
    for (int l = 0; l < 2; ++l) {
      int row = l * 32 + wv * 8 + rowL;
      gload_lds16(A + (tileM + row) * 1024 + k0 + kc, &As[l * 2048 + wv * 512]);
      gload_lds16(Bt + (tileN + row) * 1024 + k0 + kc, &Bs[l * 2048 + wv * 512]);
    }
    __syncthreads();
#pragma unroll
    for (int kk = 0; kk < 2; ++kk) {
      const int ko = kk ? ko1 : ko0;
      bf16x8 af = *(const bf16x8*)&As[(wv * 16 + lq) * 64 + ko];
#pragma unroll
      for (int ni = 0; ni < 4; ++ni) {
        bf16x8 bfr = *(const bf16x8*)&Bs[(ni * 16 + lq) * 64 + ko];
        acc[ni] = __builtin_amdgcn_mfma_f32_16x16x32_bf16(af, bfr, acc[ni], 0, 0, 0);
      }
    }
  }
#pragma unroll
  for (int ni = 0; ni < 4; ++ni) {
    int col = tileN + ni * 16 + lq;
#pragma unroll
    for (int rg = 0; rg < 4; ++rg) {
      int row = tileM + wv * 16 + quad * 4 + rg;
      C[row * 1024 + col] = acc[ni][rg] + bias[col];
    }
  }
}

// ---------------- fused synthesizer attention (uniform pairs, XCD-local) ----
// Grid (32,16): x = bh, y = p. Linear id = y*32+x -> id%8 = bh%8: all 16
// p-blocks of a bh land on one XCD; working set (vt 256KB + r 1MB + w2t
// 256KB per bh) fits its 4MB L2 -> staging drains at L2 latency.
// Body identical to the proven round-11 kernel.
__global__ __launch_bounds__(256, 2) void attn(
    const unsigned short* __restrict__ r, const unsigned short* __restrict__ w2t,
    const unsigned short* __restrict__ vt, const unsigned short* __restrict__ ebj,
    unsigned short* __restrict__ y) {
  __shared__ unsigned short W2s[2][64 * 64];
  __shared__ unsigned short Vs[2][64 * 64];
  __shared__ unsigned short Ps[4][16 * 64];

  const int tid = threadIdx.x;
  const int wv = tid >> 6, ln = tid & 63;
  const int quad = ln >> 4, lq = ln & 15;
  const int bh = blockIdx.x, b = bh >> 4, h = bh & 15;
  const int p = blockIdx.y;                       // pair (p, 31-p)
  const int ta = p, tb = 31 - p;
  const int t0a = ta * 64, t0b = tb * 64;
  const int rowL = ln >> 3;
  const int kc = (((ln & 7) ^ rowL) & 7) * 8;
  const int sx = lq & 7;
  const int ko0 = (quad ^ sx) * 8, ko1 = ((4 + quad) ^ sx) * 8;

  // R A-fragments for both tiles (L2-hot)
  bf16x8 ra[2][2];
  {
    const unsigned short* base = r + (b * 2048 + wv * 16 + lq) * 1024 + h * 64 + quad * 8;
    ra[0][0] = *(const bf16x8*)(base + t0a * 1024);
    ra[0][1] = *(const bf16x8*)(base + t0a * 1024 + 32);
    ra[1][0] = *(const bf16x8*)(base + t0b * 1024);
    ra[1][1] = *(const bf16x8*)(base + t0b * 1024 + 32);
  }

  f32x4 accY[4];
  f32x4 accL;
  const f32x4 zf = {0.f, 0.f, 0.f, 0.f};
#pragma unroll
  for (int nd = 0; nd < 4; ++nd) accY[nd] = zf;
  accL = zf;

  auto stage = [&](int jt, int bi) {
    int j0 = jt * 64;
#pragma unroll
    for (int l = 0; l < 2; ++l) {
      int row = l * 32 + wv * 8 + rowL;
      gload_lds16(w2t + (j0 + row) * 64 + kc, &W2s[bi][l * 2048 + wv * 512]);
      gload_lds16(vt + (h * 64 + row) * 4096 + b * 2048 + j0 + kc,
                  &Vs[bi][l * 2048 + wv * 512]);
    }
  };

  stage(0, 0);
  for (int it = 0; it <= 32; ++it) {
    const int cb = it & 1;
    __syncthreads();                 // staging(it) landed; other buf free
    if (it < 32) {
      int nit = it + 1;
      int njt = (nit <= p) ? nit : (nit - p - 1);
      stage(njt, cb ^ 1);
    }
    const int s = (it <= p) ? 0 : 1;
    const int jt = (it <= p) ? it : (it - p - 1);
    const int tts = s ? tb : ta;
    const int t0 = tts * 64;
    const int j0 = jt * 64;

    // ebj B-fragments for the L-MFMA
    bf16x8 eb0 = *(const bf16x8*)&ebj[j0 + quad * 8];
    bf16x8 eb1 = *(const bf16x8*)&ebj[j0 + 32 + quad * 8];
    // W2 B-fragments
    bf16x8 w2f0[4], w2f1[4];
#pragma unroll
    for (int ni = 0; ni < 4; ++ni) {
      w2f0[ni] = *(const bf16x8*)&W2s[cb][(ni * 16 + lq) * 64 + ko0];
      w2f1[ni] = *(const bf16x8*)&W2s[cb][(ni * 16 + lq) * 64 + ko1];
    }

    // S = R(16x64) @ W2^T -> C rows t=quad*4+rg, col j=lq (per ni)
    f32x4 sv[4] = {zf, zf, zf, zf};
#pragma unroll
    for (int ni = 0; ni < 4; ++ni) {
      sv[ni] = __builtin_amdgcn_mfma_f32_16x16x32_bf16(ra[s][0], w2f0[ni], sv[ni], 0, 0, 0);
      sv[ni] = __builtin_amdgcn_mfma_f32_16x16x32_bf16(ra[s][1], w2f1[ni], sv[ni], 0, 0, 0);
    }

    // exp (+ causal mask on diag tile), write P to LDS (A-layout, swizzled)
    const bool diag = (jt == tts);
#pragma unroll
    for (int ni = 0; ni < 4; ++ni) {
      int j = j0 + ni * 16 + lq;
#pragma unroll
      for (int rg = 0; rg < 4; ++rg) {
        float pe = __expf(sv[ni][rg]);
        if (diag) {
          int t = t0 + wv * 16 + quad * 4 + rg;
          pe = (j <= t) ? pe : 0.f;
        }
        Ps[wv][(quad * 4 + rg) * 64 +
               (((ni * 2 + (lq >> 3)) ^ ((quad * 4 + rg) & 7)) * 8) + (lq & 7)] = f2bf_fast(pe);
      }
    }

    // Y += P(16x64) @ V(64x64); L += P @ ebj
#pragma unroll
    for (int kk = 0; kk < 2; ++kk) {
      const int ko = kk ? ko1 : ko0;
      bf16x8 pa = *(const bf16x8*)&Ps[wv][lq * 64 + ko];
#pragma unroll
      for (int nd = 0; nd < 4; ++nd) {
        bf16x8 bb = *(const bf16x8*)&Vs[cb][(nd * 16 + lq) * 64 + ko];
        accY[nd] = __builtin_amdgcn_mfma_f32_16x16x32_bf16(pa, bb, accY[nd], 0, 0, 0);
      }
      accL = __builtin_amdgcn_mfma_f32_16x16x32_bf16(pa, kk ? eb1 : eb0, accL, 0, 0, 0);
    }

    // phase epilogue: write this tile's y, reset accumulators for phase B
    if (it == p || it == 32) {
      float inv[4];
#pragma unroll
      for (int rg = 0; rg < 4; ++rg) inv[rg] = __builtin_amdgcn_rcpf(accL[rg]);
#pragma unroll
      for (int nd = 0; nd < 4; ++nd)
#pragma unroll
        for (int rg = 0; rg < 4; ++rg) {
          int t = t0 + wv * 16 + quad * 4 + rg;
          y[(b * 2048 + t) * 1024 + h * 64 + nd * 16 + lq] = f2bf(accY[nd][rg] * inv[rg]);
        }
#pragma unroll
      for (int nd = 0; nd < 4; ++nd) accY[nd] = zf;
      accL = zf;
    }
  }
}

// ---------------- launch ----------------
extern "C" void kernel_launch(void* const* d_in, const int* in_sizes, int n_in,
                              void* d_out, int out_size, void* d_ws, size_t ws_size,
                              hipStream_t stream) {
  const float* x  = (const float*)d_in[0];
  const float* W1 = (const float*)d_in[1];
  const float* b1 = (const float*)d_in[2];
  const float* w2 = (const float*)d_in[3];
  const float* b2 = (const float*)d_in[4];
  const float* Wv = (const float*)d_in[5];
  const float* bv = (const float*)d_in[6];
  const float* Wp = (const float*)d_in[7];
  const float* bp = (const float*)d_in[8];

  unsigned short* ws  = (unsigned short*)d_ws;
  unsigned short* xb   = ws;                 // 4096x1024 bf16
  unsigned short* W1b  = ws + 4194304;       // 1024x1024
  unsigned short* Wvb  = ws + 5242880;       // 1024x1024
  unsigned short* Wpb  = ws + 6291456;       // 1024x1024
  unsigned short* w2t  = ws + 7340032;       // 2048x64
  unsigned short* rb   = ws + 7471104;       // 4096x1024
  unsigned short* vt   = ws + 11665408;      // 1024x4096
  unsigned short* yb   = ws + 15859712;      // 4096x1024 bf16
  unsigned short* ebjb = ws + 20054016;      // 2048 bf16

  prep<<<7298, 256, 0, stream>>>(x, W1, Wv, Wp, w2, b2, xb, W1b, Wvb, Wpb, w2t, ebjb);
  gemm_rv<<<dim3(32, 16), 256, 0, stream>>>(xb, W1b, Wvb, b1, bv, b2, rb, vt);
  attn<<<dim3(32, 16), 256, 0, stream>>>(rb, w2t, vt, ebjb, yb);
  gemm_p<<<dim3(16, 64), 256, 0, stream>>>(yb, Wpb, bp, (float*)d_out);
}

// Round 13
// 171.901 us; speedup vs baseline: 1.0978x; 1.0613x over previous
//
#include <hip/hip_runtime.h>

typedef __bf16 bf16x8 __attribute__((ext_vector_type(8)));
typedef float f32x4 __attribute__((ext_vector_type(4)));

__device__ __forceinline__ unsigned short f2bf(float f) {
  union { float f; unsigned u; } v; v.f = f;
  unsigned u = v.u;
  return (unsigned short)((u + 0x7fffu + ((u >> 16) & 1u)) >> 16);  // RNE
}
__device__ __forceinline__ unsigned short f2bf_fast(float f) {
  union { float f; unsigned u; } v; v.f = f;
  return (unsigned short)((v.u + 0x8000u) >> 16);  // round-half-up, for P only
}
__device__ __forceinline__ void gload_lds16(const void* g, void* l) {
  __builtin_amdgcn_global_load_lds(
      (const __attribute__((address_space(1))) unsigned int*)g,
      (__attribute__((address_space(3))) unsigned int*)l, 16, 0, 0);
}
__device__ __forceinline__ void cvt4(const float* __restrict__ s,
                                     unsigned short* __restrict__ d, int u) {
  f32x4 v = ((const f32x4*)s)[u];
  union { unsigned short s[4]; unsigned long long u; } o;
  o.s[0] = f2bf(v[0]); o.s[1] = f2bf(v[1]); o.s[2] = f2bf(v[2]); o.s[3] = f2bf(v[3]);
  ((unsigned long long*)d)[u] = o.u;
}

// LDS tile swizzle: row r, 16B-chunk c stored at chunk position c ^ (r&7).
// Staging lane fetches global chunk (ln&7)^(ln>>3); reads XOR chunk with lq&7.

// ---------------- prep: f32->bf16 conversions + ebj, one launch -------------
__global__ void prep(const float* __restrict__ x, const float* __restrict__ W1,
                     const float* __restrict__ Wv, const float* __restrict__ Wp,
                     const float* __restrict__ w2, const float* __restrict__ b2,
                     unsigned short* __restrict__ xb, unsigned short* __restrict__ W1b,
                     unsigned short* __restrict__ Wvb, unsigned short* __restrict__ Wpb,
                     unsigned short* __restrict__ w2t, unsigned short* __restrict__ ebj) {
  int u = blockIdx.x * 256 + threadIdx.x;
  if (u < 1048576) { cvt4(x, xb, u); return; }
  u -= 1048576;
  if (u < 262144) { cvt4(W1, W1b, u); return; }
  u -= 262144;
  if (u < 262144) { cvt4(Wv, Wvb, u); return; }
  u -= 262144;
  if (u < 262144) { cvt4(Wp, Wpb, u); return; }
  u -= 262144;
  if (u < 32768) {
    // w2 (64,2048) f32 -> w2t (2048,64) bf16
    int j = u >> 4, d4 = (u & 15) * 4;
    union { unsigned short s[4]; unsigned long long x; } o;
#pragma unroll
    for (int i = 0; i < 4; ++i) o.s[i] = f2bf(w2[(d4 + i) * 2048 + j]);
    ((unsigned long long*)w2t)[u] = o.x;
    return;
  }
  u -= 32768;
  // ebj = bf16(exp(b2)), 2048 elems in 512 x4-units
  union { unsigned short s[4]; unsigned long long x; } o;
#pragma unroll
  for (int i = 0; i < 4; ++i) o.s[i] = f2bf(__expf(b2[u * 4 + i]));
  ((unsigned long long*)ebj)[u] = o.x;
}

// ---------------- fused r & vt GEMM: shared xb tile ------------------------
// Block (tokT=x, nT=y), grid (32,16). Stages xb[128tok x 64k] ONCE; uses it
// as A for r (rb = relu(xb@W1^T+b1)) and as B for vt (vt = (Wv@xb^T+bv)*eb).
__global__ __launch_bounds__(256) void gemm_rv(
    const unsigned short* __restrict__ xb, const unsigned short* __restrict__ W1b,
    const unsigned short* __restrict__ Wvb, const float* __restrict__ b1,
    const float* __restrict__ bv, const float* __restrict__ b2,
    unsigned short* __restrict__ rb, unsigned short* __restrict__ vtb) {
  __shared__ unsigned short Xs[128 * 64];
  __shared__ unsigned short W1s[64 * 64];
  __shared__ unsigned short Wvs[64 * 64];
  const int tm = blockIdx.x * 128, n0 = blockIdx.y * 64;
  const int tid = threadIdx.x;
  const int wv = tid >> 6, ln = tid & 63;
  const int quad = ln >> 4, lq = ln & 15;
  const int rowL = ln >> 3;
  const int kc = (((ln & 7) ^ rowL) & 7) * 8;
  const int sx = lq & 7;
  const int ko0 = (quad ^ sx) * 8, ko1 = ((4 + quad) ^ sx) * 8;

  f32x4 accR[2][4];
  f32x4 accV[8];
  const f32x4 zf = {0.f, 0.f, 0.f, 0.f};
#pragma unroll
  for (int i = 0; i < 2; ++i)
#pragma unroll
    for (int j = 0; j < 4; ++j) accR[i][j] = zf;
#pragma unroll
  for (int j = 0; j < 8; ++j) accV[j] = zf;

  for (int k0 = 0; k0 < 1024; k0 += 64) {
    __syncthreads();
#pragma unroll
    for (int l = 0; l < 4; ++l) {
      int row = l * 32 + wv * 8 + rowL;
      gload_lds16(xb + (tm + row) * 1024 + k0 + kc, &Xs[l * 2048 + wv * 512]);
    }
#pragma unroll
    for (int l = 0; l < 2; ++l) {
      int row = l * 32 + wv * 8 + rowL;
      gload_lds16(W1b + (n0 + row) * 1024 + k0 + kc, &W1s[l * 2048 + wv * 512]);
      gload_lds16(Wvb + (n0 + row) * 1024 + k0 + kc, &Wvs[l * 2048 + wv * 512]);
    }
    __syncthreads();
#pragma unroll
    for (int kk = 0; kk < 2; ++kk) {
      const int ko = kk ? ko1 : ko0;
      bf16x8 xa[2], w1f[4];
#pragma unroll
      for (int mi = 0; mi < 2; ++mi)
        xa[mi] = *(const bf16x8*)&Xs[(wv * 32 + mi * 16 + lq) * 64 + ko];
#pragma unroll
      for (int ni = 0; ni < 4; ++ni)
        w1f[ni] = *(const bf16x8*)&W1s[(ni * 16 + lq) * 64 + ko];
#pragma unroll
      for (int mi = 0; mi < 2; ++mi)
#pragma unroll
        for (int ni = 0; ni < 4; ++ni)
          accR[mi][ni] = __builtin_amdgcn_mfma_f32_16x16x32_bf16(xa[mi], w1f[ni], accR[mi][ni], 0, 0, 0);
      bf16x8 wva = *(const bf16x8*)&Wvs[(wv * 16 + lq) * 64 + ko];
#pragma unroll
      for (int nj = 0; nj < 8; ++nj) {
        bf16x8 xbf = *(const bf16x8*)&Xs[(nj * 16 + lq) * 64 + ko];
        accV[nj] = __builtin_amdgcn_mfma_f32_16x16x32_bf16(wva, xbf, accV[nj], 0, 0, 0);
      }
    }
  }
  // epilogue r
#pragma unroll
  for (int ni = 0; ni < 4; ++ni) {
    int col = n0 + ni * 16 + lq;
    float bc = b1[col];
#pragma unroll
    for (int mi = 0; mi < 2; ++mi)
#pragma unroll
      for (int rg = 0; rg < 4; ++rg) {
        int row = tm + wv * 32 + mi * 16 + quad * 4 + rg;
        float v = accR[mi][ni][rg] + bc;
        rb[row * 1024 + col] = f2bf(v > 0.f ? v : 0.f);
      }
  }
  // epilogue vt
#pragma unroll
  for (int nj = 0; nj < 8; ++nj) {
    int tok = tm + nj * 16 + lq;
    float eb = __expf(b2[tok & 2047]);
#pragma unroll
    for (int rg = 0; rg < 4; ++rg) {
      int ch = n0 + wv * 16 + quad * 4 + rg;
      vtb[ch * 4096 + tok] = f2bf((accV[nj][rg] + bv[ch]) * eb);
    }
  }
}

// ---------------- final GEMM: d_out = yb @ Wp^T + bp (f32 out) --------------
// 64M x 64N tiles -> grid (16,64) = 1024 blocks = 4/CU (16KB LDS).
__global__ __launch_bounds__(256) void gemm_p(
    const unsigned short* __restrict__ A, const unsigned short* __restrict__ Bt,
    const float* __restrict__ bias, float* __restrict__ C) {
  __shared__ unsigned short As[64 * 64];
  __shared__ unsigned short Bs[64 * 64];
  const int tid = threadIdx.x;
  const int wv = tid >> 6, ln = tid & 63;
  const int quad = ln >> 4, lq = ln & 15;
  const int tileM = blockIdx.y * 64, tileN = blockIdx.x * 64;
  const int rowL = ln >> 3;
  const int kc = (((ln & 7) ^ rowL) & 7) * 8;
  const int sx = lq & 7;
  const int ko0 = (quad ^ sx) * 8, ko1 = ((4 + quad) ^ sx) * 8;

  f32x4 acc[4];
  const f32x4 zf = {0.f, 0.f, 0.f, 0.f};
#pragma unroll
  for (int j = 0; j < 4; ++j) acc[j] = zf;

  for (int k0 = 0; k0 < 1024; k0 += 64) {
    __syncthreads();
#pragma unroll
    for (int l = 0; l < 2; ++l) {
      int row = l * 32 + wv * 8 + rowL;
      gload_lds16(A + (tileM + row) * 1024 + k0 + kc, &As[l * 2048 + wv * 512]);
      gload_lds16(Bt + (tileN + row) * 1024 + k0 + kc, &Bs[l * 2048 + wv * 512]);
    }
    __syncthreads();
#pragma unroll
    for (int kk = 0; kk < 2; ++kk) {
      const int ko = kk ? ko1 : ko0;
      bf16x8 af = *(const bf16x8*)&As[(wv * 16 + lq) * 64 + ko];
#pragma unroll
      for (int ni = 0; ni < 4; ++ni) {
        bf16x8 bfr = *(const bf16x8*)&Bs[(ni * 16 + lq) * 64 + ko];
        acc[ni] = __builtin_amdgcn_mfma_f32_16x16x32_bf16(af, bfr, acc[ni], 0, 0, 0);
      }
    }
  }
#pragma unroll
  for (int ni = 0; ni < 4; ++ni) {
    int col = tileN + ni * 16 + lq;
#pragma unroll
    for (int rg = 0; rg < 4; ++rg) {
      int row = tileM + wv * 16 + quad * 4 + rg;
      C[row * 1024 + col] = acc[ni][rg] + bias[col];
    }
  }
}

// ---------------- fused synthesizer attention (shared-j concurrent pairs) ---
// Block = tiles (p, 31-p) sharing ONE j-loop jt=0..31-p; V/W2 staged once per
// jt; tile-a computed while jt<=p (its y written at jt==p). W2/ebj fragments
// loaded once per interval feed both tiles. Grid (32,16): x=bh (XCD-local),
// y=q with p = q<8 ? q : 23-q -> co-resident blocks (q,q+8) total 49
// intervals per CU, uniform across CUs.
__global__ __launch_bounds__(256, 2) void attn(
    const unsigned short* __restrict__ r, const unsigned short* __restrict__ w2t,
    const unsigned short* __restrict__ vt, const unsigned short* __restrict__ ebj,
    unsigned short* __restrict__ y) {
  __shared__ unsigned short W2s[2][64 * 64];
  __shared__ unsigned short Vs[2][64 * 64];
  __shared__ unsigned short Ps[4][16 * 64];

  const int tid = threadIdx.x;
  const int wv = tid >> 6, ln = tid & 63;
  const int quad = ln >> 4, lq = ln & 15;
  const int bh = blockIdx.x, b = bh >> 4, h = bh & 15;
  const int q = blockIdx.y;
  const int p = (q < 8) ? q : 23 - q;             // pair (p, 31-p)
  const int ta = p, tb = 31 - p;
  const int t0a = ta * 64, t0b = tb * 64;
  const int rowL = ln >> 3;
  const int kc = (((ln & 7) ^ rowL) & 7) * 8;
  const int sx = lq & 7;
  const int ko0 = (quad ^ sx) * 8, ko1 = ((4 + quad) ^ sx) * 8;

  // R A-fragments for both tiles (L2-hot)
  bf16x8 ra[2][2];
  {
    const unsigned short* base = r + (b * 2048 + wv * 16 + lq) * 1024 + h * 64 + quad * 8;
    ra[0][0] = *(const bf16x8*)(base + t0a * 1024);
    ra[0][1] = *(const bf16x8*)(base + t0a * 1024 + 32);
    ra[1][0] = *(const bf16x8*)(base + t0b * 1024);
    ra[1][1] = *(const bf16x8*)(base + t0b * 1024 + 32);
  }

  f32x4 accY[2][4];
  f32x4 accL[2];
  const f32x4 zf = {0.f, 0.f, 0.f, 0.f};
#pragma unroll
  for (int s = 0; s < 2; ++s) {
    accL[s] = zf;
#pragma unroll
    for (int nd = 0; nd < 4; ++nd) accY[s][nd] = zf;
  }

  auto stage = [&](int jt, int bi) {
    int j0 = jt * 64;
#pragma unroll
    for (int l = 0; l < 2; ++l) {
      int row = l * 32 + wv * 8 + rowL;
      gload_lds16(w2t + (j0 + row) * 64 + kc, &W2s[bi][l * 2048 + wv * 512]);
      gload_lds16(vt + (h * 64 + row) * 4096 + b * 2048 + j0 + kc,
                  &Vs[bi][l * 2048 + wv * 512]);
    }
  };

#define TILE(S, T0, TT)                                                         \
    {                                                                           \
      f32x4 sv[4] = {zf, zf, zf, zf};                                           \
      _Pragma("unroll") for (int ni = 0; ni < 4; ++ni) {                        \
        sv[ni] = __builtin_amdgcn_mfma_f32_16x16x32_bf16(ra[S][0], w2f0[ni], sv[ni], 0, 0, 0); \
        sv[ni] = __builtin_amdgcn_mfma_f32_16x16x32_bf16(ra[S][1], w2f1[ni], sv[ni], 0, 0, 0); \
      }                                                                         \
      const bool diag = (jt == (TT));                                           \
      _Pragma("unroll") for (int ni = 0; ni < 4; ++ni) {                        \
        int j = j0 + ni * 16 + lq;                                              \
        _Pragma("unroll") for (int rg = 0; rg < 4; ++rg) {                      \
          float pe = __expf(sv[ni][rg]);                                        \
          if (diag) {                                                           \
            int t = (T0) + wv * 16 + quad * 4 + rg;                             \
            pe = (j <= t) ? pe : 0.f;                                           \
          }                                                                     \
          Ps[wv][(quad * 4 + rg) * 64 +                                         \
                 (((ni * 2 + (lq >> 3)) ^ ((quad * 4 + rg) & 7)) * 8) + (lq & 7)] = f2bf_fast(pe); \
        }                                                                       \
      }                                                                         \
      _Pragma("unroll") for (int kk = 0; kk < 2; ++kk) {                        \
        const int ko = kk ? ko1 : ko0;                                          \
        bf16x8 pa = *(const bf16x8*)&Ps[wv][lq * 64 + ko];                      \
        _Pragma("unroll") for (int nd = 0; nd < 4; ++nd) {                      \
          bf16x8 bb = *(const bf16x8*)&Vs[cb][(nd * 16 + lq) * 64 + ko];        \
          accY[S][nd] = __builtin_amdgcn_mfma_f32_16x16x32_bf16(pa, bb, accY[S][nd], 0, 0, 0); \
        }                                                                       \
        accL[S] = __builtin_amdgcn_mfma_f32_16x16x32_bf16(pa, kk ? eb1 : eb0, accL[S], 0, 0, 0); \
      }                                                                         \
    }

#define WRITEOUT(S, T0)                                                         \
    {                                                                           \
      float inv[4];                                                             \
      _Pragma("unroll") for (int rg = 0; rg < 4; ++rg)                          \
        inv[rg] = __builtin_amdgcn_rcpf(accL[S][rg]);                           \
      _Pragma("unroll") for (int nd = 0; nd < 4; ++nd)                          \
        _Pragma("unroll") for (int rg = 0; rg < 4; ++rg) {                      \
          int t = (T0) + wv * 16 + quad * 4 + rg;                               \
          y[(b * 2048 + t) * 1024 + h * 64 + nd * 16 + lq] =                    \
              f2bf(accY[S][nd][rg] * inv[rg]);                                  \
        }                                                                       \
    }

  stage(0, 0);
  for (int jt = 0; jt <= tb; ++jt) {
    const int cb = jt & 1;
    __syncthreads();                 // staging(jt) landed; other buf free
    if (jt < tb) stage(jt + 1, cb ^ 1);
    const int j0 = jt * 64;

    // shared per-interval fragments: ebj + W2 (feed both tiles)
    bf16x8 eb0 = *(const bf16x8*)&ebj[j0 + quad * 8];
    bf16x8 eb1 = *(const bf16x8*)&ebj[j0 + 32 + quad * 8];
    bf16x8 w2f0[4], w2f1[4];
#pragma unroll
    for (int ni = 0; ni < 4; ++ni) {
      w2f0[ni] = *(const bf16x8*)&W2s[cb][(ni * 16 + lq) * 64 + ko0];
      w2f1[ni] = *(const bf16x8*)&W2s[cb][(ni * 16 + lq) * 64 + ko1];
    }

    if (jt <= ta) TILE(0, t0a, ta);
    TILE(1, t0b, tb);
    if (jt == ta) WRITEOUT(0, t0a);
  }
  WRITEOUT(1, t0b);
#undef TILE
#undef WRITEOUT
}

// ---------------- launch ----------------
extern "C" void kernel_launch(void* const* d_in, const int* in_sizes, int n_in,
                              void* d_out, int out_size, void* d_ws, size_t ws_size,
                              hipStream_t stream) {
  const float* x  = (const float*)d_in[0];
  const float* W1 = (const float*)d_in[1];
  const float* b1 = (const float*)d_in[2];
  const float* w2 = (const float*)d_in[3];
  const float* b2 = (const float*)d_in[4];
  const float* Wv = (const float*)d_in[5];
  const float* bv = (const float*)d_in[6];
  const float* Wp = (const float*)d_in[7];
  const float* bp = (const float*)d_in[8];

  unsigned short* ws  = (unsigned short*)d_ws;
  unsigned short* xb   = ws;                 // 4096x1024 bf16
  unsigned short* W1b  = ws + 4194304;       // 1024x1024
  unsigned short* Wvb  = ws + 5242880;       // 1024x1024
  unsigned short* Wpb  = ws + 6291456;       // 1024x1024
  unsigned short* w2t  = ws + 7340032;       // 2048x64
  unsigned short* rb   = ws + 7471104;       // 4096x1024
  unsigned short* vt   = ws + 11665408;      // 1024x4096
  unsigned short* yb   = ws + 15859712;      // 4096x1024 bf16
  unsigned short* ebjb = ws + 20054016;      // 2048 bf16

  prep<<<7298, 256, 0, stream>>>(x, W1, Wv, Wp, w2, b2, xb, W1b, Wvb, Wpb, w2t, ebjb);
  gemm_rv<<<dim3(32, 16), 256, 0, stream>>>(xb, W1b, Wvb, b1, bv, b2, rb, vt);
  attn<<<dim3(32, 16), 256, 0, stream>>>(rb, w2t, vt, ebjb, yb);
  gemm_p<<<dim3(16, 64), 256, 0, stream>>>(yb, Wpb, bp, (float*)d_out);
}

// Round 14
// 170.260 us; speedup vs baseline: 1.1084x; 1.0096x over previous
//
#include <hip/hip_runtime.h>

typedef __bf16 bf16x8 __attribute__((ext_vector_type(8)));
typedef float f32x4 __attribute__((ext_vector_type(4)));

__device__ __forceinline__ unsigned short f2bf(float f) {
  union { float f; unsigned u; } v; v.f = f;
  unsigned u = v.u;
  return (unsigned short)((u + 0x7fffu + ((u >> 16) & 1u)) >> 16);  // RNE
}
__device__ __forceinline__ unsigned short f2bf_fast(float f) {
  union { float f; unsigned u; } v; v.f = f;
  return (unsigned short)((v.u + 0x8000u) >> 16);  // round-half-up, for P only
}
__device__ __forceinline__ void gload_lds16(const void* g, void* l) {
  __builtin_amdgcn_global_load_lds(
      (const __attribute__((address_space(1))) unsigned int*)g,
      (__attribute__((address_space(3))) unsigned int*)l, 16, 0, 0);
}
__device__ __forceinline__ void cvt4(const float* __restrict__ s,
                                     unsigned short* __restrict__ d, int u) {
  f32x4 v = ((const f32x4*)s)[u];
  union { unsigned short s[4]; unsigned long long u; } o;
  o.s[0] = f2bf(v[0]); o.s[1] = f2bf(v[1]); o.s[2] = f2bf(v[2]); o.s[3] = f2bf(v[3]);
  ((unsigned long long*)d)[u] = o.u;
}

// LDS tile swizzle (128B rows): row r, 16B-chunk c stored at position c^(r&7).
// Staging lane fetches global chunk (ln&7)^(ln>>3); reads XOR chunk with lq&7.
// For 256B rows (BK=128): chunk c (0..15) at position (c&8)|((c&7)^(r&7)).

// ---------------- prep: f32->bf16 conversions + ebj, one launch -------------
__global__ void prep(const float* __restrict__ x, const float* __restrict__ W1,
                     const float* __restrict__ Wv, const float* __restrict__ Wp,
                     const float* __restrict__ w2, const float* __restrict__ b2,
                     unsigned short* __restrict__ xb, unsigned short* __restrict__ W1b,
                     unsigned short* __restrict__ Wvb, unsigned short* __restrict__ Wpb,
                     unsigned short* __restrict__ w2t, unsigned short* __restrict__ ebj) {
  int u = blockIdx.x * 256 + threadIdx.x;
  if (u < 1048576) { cvt4(x, xb, u); return; }
  u -= 1048576;
  if (u < 262144) { cvt4(W1, W1b, u); return; }
  u -= 262144;
  if (u < 262144) { cvt4(Wv, Wvb, u); return; }
  u -= 262144;
  if (u < 262144) { cvt4(Wp, Wpb, u); return; }
  u -= 262144;
  if (u < 32768) {
    // w2 (64,2048) f32 -> w2t (2048,64) bf16
    int j = u >> 4, d4 = (u & 15) * 4;
    union { unsigned short s[4]; unsigned long long x; } o;
#pragma unroll
    for (int i = 0; i < 4; ++i) o.s[i] = f2bf(w2[(d4 + i) * 2048 + j]);
    ((unsigned long long*)w2t)[u] = o.x;
    return;
  }
  u -= 32768;
  // ebj = bf16(exp(b2)), 2048 elems in 512 x4-units
  union { unsigned short s[4]; unsigned long long x; } o;
#pragma unroll
  for (int i = 0; i < 4; ++i) o.s[i] = f2bf(__expf(b2[u * 4 + i]));
  ((unsigned long long*)ebj)[u] = o.x;
}

// ---------------- fused r & vt GEMM: 64-token blocks, 4/CU ------------------
// Block (tokT=x 0..63, nT=y 0..15), grid (64,16)=1024 blocks = 4/CU (24KB).
// Stages xb[64tok x 64k] once; A for r (relu(xb@W1^T+b1)), B for vt
// ((Wv@xb^T+bv)*exp(b2)). Per wave-interval: 6 gll, 20 ds_read, 16 MFMA.
// id%8 = x%8 -> xb strip L2-co-located per XCD.
__global__ __launch_bounds__(256) void gemm_rv(
    const unsigned short* __restrict__ xb, const unsigned short* __restrict__ W1b,
    const unsigned short* __restrict__ Wvb, const float* __restrict__ b1,
    const float* __restrict__ bv, const float* __restrict__ b2,
    unsigned short* __restrict__ rb, unsigned short* __restrict__ vtb) {
  __shared__ unsigned short Xs[64 * 64];
  __shared__ unsigned short W1s[64 * 64];
  __shared__ unsigned short Wvs[64 * 64];
  const int tm = blockIdx.x * 64, n0 = blockIdx.y * 64;
  const int tid = threadIdx.x;
  const int wv = tid >> 6, ln = tid & 63;
  const int quad = ln >> 4, lq = ln & 15;
  const int rowL = ln >> 3;
  const int kc = (((ln & 7) ^ rowL) & 7) * 8;
  const int sx = lq & 7;
  const int ko0 = (quad ^ sx) * 8, ko1 = ((4 + quad) ^ sx) * 8;

  f32x4 accR[4], accV[4];
  const f32x4 zf = {0.f, 0.f, 0.f, 0.f};
#pragma unroll
  for (int j = 0; j < 4; ++j) { accR[j] = zf; accV[j] = zf; }

  for (int k0 = 0; k0 < 1024; k0 += 64) {
    __syncthreads();
#pragma unroll
    for (int l = 0; l < 2; ++l) {
      int row = l * 32 + wv * 8 + rowL;
      gload_lds16(xb + (tm + row) * 1024 + k0 + kc, &Xs[l * 2048 + wv * 512]);
      gload_lds16(W1b + (n0 + row) * 1024 + k0 + kc, &W1s[l * 2048 + wv * 512]);
      gload_lds16(Wvb + (n0 + row) * 1024 + k0 + kc, &Wvs[l * 2048 + wv * 512]);
    }
    __syncthreads();
#pragma unroll
    for (int kk = 0; kk < 2; ++kk) {
      const int ko = kk ? ko1 : ko0;
      bf16x8 xa  = *(const bf16x8*)&Xs[(wv * 16 + lq) * 64 + ko];
      bf16x8 wva = *(const bf16x8*)&Wvs[(wv * 16 + lq) * 64 + ko];
#pragma unroll
      for (int ni = 0; ni < 4; ++ni) {
        bf16x8 w1f = *(const bf16x8*)&W1s[(ni * 16 + lq) * 64 + ko];
        accR[ni] = __builtin_amdgcn_mfma_f32_16x16x32_bf16(xa, w1f, accR[ni], 0, 0, 0);
      }
#pragma unroll
      for (int nj = 0; nj < 4; ++nj) {
        bf16x8 xbf = *(const bf16x8*)&Xs[(nj * 16 + lq) * 64 + ko];
        accV[nj] = __builtin_amdgcn_mfma_f32_16x16x32_bf16(wva, xbf, accV[nj], 0, 0, 0);
      }
    }
  }
  // epilogue r: rows = tokens tm+wv*16+quad*4+rg, cols n0+ni*16+lq
#pragma unroll
  for (int ni = 0; ni < 4; ++ni) {
    int col = n0 + ni * 16 + lq;
    float bc = b1[col];
#pragma unroll
    for (int rg = 0; rg < 4; ++rg) {
      int row = tm + wv * 16 + quad * 4 + rg;
      float v = accR[ni][rg] + bc;
      rb[row * 1024 + col] = f2bf(v > 0.f ? v : 0.f);
    }
  }
  // epilogue vt: rows = channels n0+wv*16+quad*4+rg, cols tokens tm+nj*16+lq
  float bvv[4];
#pragma unroll
  for (int rg = 0; rg < 4; ++rg) bvv[rg] = bv[n0 + wv * 16 + quad * 4 + rg];
#pragma unroll
  for (int nj = 0; nj < 4; ++nj) {
    int tok = tm + nj * 16 + lq;
    float eb = __expf(b2[tok & 2047]);
#pragma unroll
    for (int rg = 0; rg < 4; ++rg) {
      int ch = n0 + wv * 16 + quad * 4 + rg;
      vtb[ch * 4096 + tok] = f2bf((accV[nj][rg] + bvv[rg]) * eb);
    }
  }
}

// ---------------- final GEMM: d_out = yb @ Wp^T + bp (f32 out) --------------
// 64M x 64N tiles, BK=128 -> 8 intervals of 16 MFMA/wave. LDS 32KB, grid
// (16,64)=1024 blocks = 4/CU. 256B LDS rows, chunk c at (c&8)|((c&7)^(r&7)).
__global__ __launch_bounds__(256) void gemm_p(
    const unsigned short* __restrict__ A, const unsigned short* __restrict__ Bt,
    const float* __restrict__ bias, float* __restrict__ C) {
  __shared__ unsigned short As[64 * 128];
  __shared__ unsigned short Bs[64 * 128];
  const int tid = threadIdx.x;
  const int wv = tid >> 6, ln = tid & 63;
  const int quad = ln >> 4, lq = ln & 15;
  const int tileM = blockIdx.y * 64, tileN = blockIdx.x * 64;
  const int srow = ln >> 4, pos = ln & 15;

  f32x4 acc[4];
  const f32x4 zf = {0.f, 0.f, 0.f, 0.f};
#pragma unroll
  for (int j = 0; j < 4; ++j) acc[j] = zf;

  // per-kk fragment chunk offsets
  int kof[4];
#pragma unroll
  for (int kk = 0; kk < 4; ++kk) {
    int c = kk * 4 + quad;
    kof[kk] = (((c & 8) | ((c & 7) ^ (lq & 7)))) * 8;
  }

  for (int k0 = 0; k0 < 1024; k0 += 128) {
    __syncthreads();
#pragma unroll
    for (int l = 0; l < 4; ++l) {
      int row = l * 16 + wv * 4 + srow;
      int cs = (pos & 8) | ((pos & 7) ^ (row & 7));
      gload_lds16(A + (tileM + row) * 1024 + k0 + cs * 8, &As[(l * 16 + wv * 4) * 128]);
      gload_lds16(Bt + (tileN + row) * 1024 + k0 + cs * 8, &Bs[(l * 16 + wv * 4) * 128]);
    }
    __syncthreads();
#pragma unroll
    for (int kk = 0; kk < 4; ++kk) {
      const int ko = kof[kk];
      bf16x8 af = *(const bf16x8*)&As[(wv * 16 + lq) * 128 + ko];
#pragma unroll
      for (int ni = 0; ni < 4; ++ni) {
        bf16x8 bfr = *(const bf16x8*)&Bs[(ni * 16 + lq) * 128 + ko];
        acc[ni] = __builtin_amdgcn_mfma_f32_16x16x32_bf16(af, bfr, acc[ni], 0, 0, 0);
      }
    }
  }
#pragma unroll
  for (int ni = 0; ni < 4; ++ni) {
    int col = tileN + ni * 16 + lq;
#pragma unroll
    for (int rg = 0; rg < 4; ++rg) {
      int row = tileM + wv * 16 + quad * 4 + rg;
      C[row * 1024 + col] = acc[ni][rg] + bias[col];
    }
  }
}

// ---------------- fused synthesizer attention (shared-j concurrent pairs) ---
// Block = tiles (p, 31-p) sharing ONE j-loop jt=0..31-p; V/W2 staged once per
// jt; tile-a computed while jt<=p (its y written at jt==p). W2/ebj fragments
// loaded once per interval feed both tiles. Grid (32,16): x=bh (XCD-local),
// y=q with p = q<8 ? q : 23-q -> co-resident blocks (q,q+8) total 49
// intervals per CU, uniform across CUs.
__global__ __launch_bounds__(256, 2) void attn(
    const unsigned short* __restrict__ r, const unsigned short* __restrict__ w2t,
    const unsigned short* __restrict__ vt, const unsigned short* __restrict__ ebj,
    unsigned short* __restrict__ y) {
  __shared__ unsigned short W2s[2][64 * 64];
  __shared__ unsigned short Vs[2][64 * 64];
  __shared__ unsigned short Ps[4][16 * 64];

  const int tid = threadIdx.x;
  const int wv = tid >> 6, ln = tid & 63;
  const int quad = ln >> 4, lq = ln & 15;
  const int bh = blockIdx.x, b = bh >> 4, h = bh & 15;
  const int q = blockIdx.y;
  const int p = (q < 8) ? q : 23 - q;             // pair (p, 31-p)
  const int ta = p, tb = 31 - p;
  const int t0a = ta * 64, t0b = tb * 64;
  const int rowL = ln >> 3;
  const int kc = (((ln & 7) ^ rowL) & 7) * 8;
  const int sx = lq & 7;
  const int ko0 = (quad ^ sx) * 8, ko1 = ((4 + quad) ^ sx) * 8;

  // R A-fragments for both tiles (L2-hot)
  bf16x8 ra[2][2];
  {
    const unsigned short* base = r + (b * 2048 + wv * 16 + lq) * 1024 + h * 64 + quad * 8;
    ra[0][0] = *(const bf16x8*)(base + t0a * 1024);
    ra[0][1] = *(const bf16x8*)(base + t0a * 1024 + 32);
    ra[1][0] = *(const bf16x8*)(base + t0b * 1024);
    ra[1][1] = *(const bf16x8*)(base + t0b * 1024 + 32);
  }

  f32x4 accY[2][4];
  f32x4 accL[2];
  const f32x4 zf = {0.f, 0.f, 0.f, 0.f};
#pragma unroll
  for (int s = 0; s < 2; ++s) {
    accL[s] = zf;
#pragma unroll
    for (int nd = 0; nd < 4; ++nd) accY[s][nd] = zf;
  }

  auto stage = [&](int jt, int bi) {
    int j0 = jt * 64;
#pragma unroll
    for (int l = 0; l < 2; ++l) {
      int row = l * 32 + wv * 8 + rowL;
      gload_lds16(w2t + (j0 + row) * 64 + kc, &W2s[bi][l * 2048 + wv * 512]);
      gload_lds16(vt + (h * 64 + row) * 4096 + b * 2048 + j0 + kc,
                  &Vs[bi][l * 2048 + wv * 512]);
    }
  };

#define TILE(S, T0, TT)                                                         \
    {                                                                           \
      f32x4 sv[4] = {zf, zf, zf, zf};                                           \
      _Pragma("unroll") for (int ni = 0; ni < 4; ++ni) {                        \
        sv[ni] = __builtin_amdgcn_mfma_f32_16x16x32_bf16(ra[S][0], w2f0[ni], sv[ni], 0, 0, 0); \
        sv[ni] = __builtin_amdgcn_mfma_f32_16x16x32_bf16(ra[S][1], w2f1[ni], sv[ni], 0, 0, 0); \
      }                                                                         \
      const bool diag = (jt == (TT));                                           \
      _Pragma("unroll") for (int ni = 0; ni < 4; ++ni) {                        \
        int j = j0 + ni * 16 + lq;                                              \
        _Pragma("unroll") for (int rg = 0; rg < 4; ++rg) {                      \
          float pe = __expf(sv[ni][rg]);                                        \
          if (diag) {                                                           \
            int t = (T0) + wv * 16 + quad * 4 + rg;                             \
            pe = (j <= t) ? pe : 0.f;                                           \
          }                                                                     \
          Ps[wv][(quad * 4 + rg) * 64 +                                         \
                 (((ni * 2 + (lq >> 3)) ^ ((quad * 4 + rg) & 7)) * 8) + (lq & 7)] = f2bf_fast(pe); \
        }                                                                       \
      }                                                                         \
      _Pragma("unroll") for (int kk = 0; kk < 2; ++kk) {                        \
        const int ko = kk ? ko1 : ko0;                                          \
        bf16x8 pa = *(const bf16x8*)&Ps[wv][lq * 64 + ko];                      \
        _Pragma("unroll") for (int nd = 0; nd < 4; ++nd) {                      \
          bf16x8 bb = *(const bf16x8*)&Vs[cb][(nd * 16 + lq) * 64 + ko];        \
          accY[S][nd] = __builtin_amdgcn_mfma_f32_16x16x32_bf16(pa, bb, accY[S][nd], 0, 0, 0); \
        }                                                                       \
        accL[S] = __builtin_amdgcn_mfma_f32_16x16x32_bf16(pa, kk ? eb1 : eb0, accL[S], 0, 0, 0); \
      }                                                                         \
    }

#define WRITEOUT(S, T0)                                                         \
    {                                                                           \
      float inv[4];                                                             \
      _Pragma("unroll") for (int rg = 0; rg < 4; ++rg)                          \
        inv[rg] = __builtin_amdgcn_rcpf(accL[S][rg]);                           \
      _Pragma("unroll") for (int nd = 0; nd < 4; ++nd)                          \
        _Pragma("unroll") for (int rg = 0; rg < 4; ++rg) {                      \
          int t = (T0) + wv * 16 + quad * 4 + rg;                               \
          y[(b * 2048 + t) * 1024 + h * 64 + nd * 16 + lq] =                    \
              f2bf(accY[S][nd][rg] * inv[rg]);                                  \
        }                                                                       \
    }

  stage(0, 0);
  for (int jt = 0; jt <= tb; ++jt) {
    const int cb = jt & 1;
    __syncthreads();                 // staging(jt) landed; other buf free
    if (jt < tb) stage(jt + 1, cb ^ 1);
    const int j0 = jt * 64;

    // shared per-interval fragments: ebj + W2 (feed both tiles)
    bf16x8 eb0 = *(const bf16x8*)&ebj[j0 + quad * 8];
    bf16x8 eb1 = *(const bf16x8*)&ebj[j0 + 32 + quad * 8];
    bf16x8 w2f0[4], w2f1[4];
#pragma unroll
    for (int ni = 0; ni < 4; ++ni) {
      w2f0[ni] = *(const bf16x8*)&W2s[cb][(ni * 16 + lq) * 64 + ko0];
      w2f1[ni] = *(const bf16x8*)&W2s[cb][(ni * 16 + lq) * 64 + ko1];
    }

    if (jt <= ta) TILE(0, t0a, ta);
    TILE(1, t0b, tb);
    if (jt == ta) WRITEOUT(0, t0a);
  }
  WRITEOUT(1, t0b);
#undef TILE
#undef WRITEOUT
}

// ---------------- launch ----------------
extern "C" void kernel_launch(void* const* d_in, const int* in_sizes, int n_in,
                              void* d_out, int out_size, void* d_ws, size_t ws_size,
                              hipStream_t stream) {
  const float* x  = (const float*)d_in[0];
  const float* W1 = (const float*)d_in[1];
  const float* b1 = (const float*)d_in[2];
  const float* w2 = (const float*)d_in[3];
  const float* b2 = (const float*)d_in[4];
  const float* Wv = (const float*)d_in[5];
  const float* bv = (const float*)d_in[6];
  const float* Wp = (const float*)d_in[7];
  const float* bp = (const float*)d_in[8];

  unsigned short* ws  = (unsigned short*)d_ws;
  unsigned short* xb   = ws;                 // 4096x1024 bf16
  unsigned short* W1b  = ws + 4194304;       // 1024x1024
  unsigned short* Wvb  = ws + 5242880;       // 1024x1024
  unsigned short* Wpb  = ws + 6291456;       // 1024x1024
  unsigned short* w2t  = ws + 7340032;       // 2048x64
  unsigned short* rb   = ws + 7471104;       // 4096x1024
  unsigned short* vt   = ws + 11665408;      // 1024x4096
  unsigned short* yb   = ws + 15859712;      // 4096x1024 bf16
  unsigned short* ebjb = ws + 20054016;      // 2048 bf16

  prep<<<7298, 256, 0, stream>>>(x, W1, Wv, Wp, w2, b2, xb, W1b, Wvb, Wpb, w2t, ebjb);
  gemm_rv<<<dim3(64, 16), 256, 0, stream>>>(xb, W1b, Wvb, b1, bv, b2, rb, vt);
  attn<<<dim3(32, 16), 256, 0, stream>>>(rb, w2t, vt, ebjb, yb);
  gemm_p<<<dim3(16, 64), 256, 0, stream>>>(yb, Wpb, bp, (float*)d_out);
}